// Round 1
// baseline (85.551 us; speedup 1.0000x reference)
//
#include <hip/hip_runtime.h>
#include <math.h>

#define BATCH   4
#define NPTS    8192
#define THREADS 256
#define NQTOT   (2 * BATCH * NPTS)      // 65536 (dir,b,query) triples
#define CHUNK   1024                    // targets staged per LDS chunk
#define TSPLIT  4                       // target quarters per (dir,b,qgroup)
#define THALF   (NPTS / TSPLIT)         // 2048 targets per block
#define NCHUNKS (THALF / CHUNK)         // 2 chunks per block

typedef _Float16 h8  __attribute__((ext_vector_type(8)));    // 4 VGPRs
typedef float    f16v __attribute__((ext_vector_type(16)));  // 16 VGPRs

// Async global->LDS, 16B per lane. Dest must be wave-uniform base + lane*16,
// which our linear tid layout satisfies.
__device__ __forceinline__ void glds16(const void* g, void* l)
{
    __builtin_amdgcn_global_load_lds(
        (const __attribute__((address_space(1))) unsigned int*)g,
        (__attribute__((address_space(3))) unsigned int*)l, 16, 0, 0);
}

// ---------------------------------------------------------------------------
// K0: transform both point clouds into MFMA-ready split-f16 B-records.
// Point t -> th (f16) + tl (f16 residual), t~ = th+tl accurate to ~2.5e-7.
// lo record (K slots 0..7):  [-2thx,-2thy,-2thz, tth, -2thx,-2thy,-2thz, ttl]
// hi record (K slots 8..15): [-2tlx,-2tly,-2tlz, 0,0,0,0,0]
// Paired with A = [qhx,qhy,qhz,1, qlx,qly,qlz,1 | qhx,qhy,qhz,0,...] this
// makes one mfma_f32_32x32x16_f16 compute  tt - 2 q~.t~  exactly up to the
// omitted ql.tl term (~2e-5 absolute on sq).
// ---------------------------------------------------------------------------
__global__ __launch_bounds__(THREADS)
void chamfer_transform(const float* __restrict__ pred,
                       const float* __restrict__ target,
                       h8* __restrict__ trans_lo,   // 65536 records
                       h8* __restrict__ trans_hi)
{
    const int p   = blockIdx.x * THREADS + threadIdx.x;   // 0..65535
    const int arr = p >> 15;                               // 0=pred, 1=target
    const int pb  = p & 32767;                             // (b*8192 + q)

    const float* src = (arr ? target : pred) + (size_t)pb * 3;
    const float x = src[0], y = src[1], z = src[2];

    const _Float16 hx = (_Float16)x;  const float lxf = x - (float)hx;
    const _Float16 hy = (_Float16)y;  const float lyf = y - (float)hy;
    const _Float16 hz = (_Float16)z;  const float lzf = z - (float)hz;
    const _Float16 lx = (_Float16)lxf, ly = (_Float16)lyf, lz = (_Float16)lzf;

    // |t~|^2 in f32 from the split coords (consistency with the cross term)
    const float tx = (float)hx + (float)lx;
    const float ty = (float)hy + (float)ly;
    const float tz = (float)hz + (float)lz;
    const float tt = fmaf(tx, tx, fmaf(ty, ty, tz * tz));
    const _Float16 tth = (_Float16)tt;
    const _Float16 ttl = (_Float16)(tt - (float)tth);

    const _Float16 n2 = (_Float16)(-2.0f);
    h8 lo = { n2 * hx, n2 * hy, n2 * hz, tth,
              n2 * hx, n2 * hy, n2 * hz, ttl };
    h8 hi = { n2 * lx, n2 * ly, n2 * lz, (_Float16)0.0f,
              (_Float16)0.0f, (_Float16)0.0f, (_Float16)0.0f, (_Float16)0.0f };

    trans_lo[p] = lo;
    trans_hi[p] = hi;
}

// ---------------------------------------------------------------------------
// A-fragment builder: m = lane&31, k = 8*(lane>>5)+j  (32x32x16 f16 layout).
// ---------------------------------------------------------------------------
__device__ __forceinline__ h8 make_afrag(const float* __restrict__ qp, const int hi)
{
    const float x = qp[0], y = qp[1], z = qp[2];
    const _Float16 hx = (_Float16)x; const _Float16 lx = (_Float16)(x - (float)hx);
    const _Float16 hy = (_Float16)y; const _Float16 ly = (_Float16)(y - (float)hy);
    const _Float16 hz = (_Float16)z; const _Float16 lz = (_Float16)(z - (float)hz);
    const _Float16 one  = (_Float16)1.0f;
    const _Float16 zero = (_Float16)0.0f;
    if (hi == 0) return (h8){hx, hy, hz, one, lx, ly, lz, one};
    return (h8){hx, hy, hz, zero, zero, zero, zero, zero};
}

// ---------------------------------------------------------------------------
// K1: per-wave 64-query (2 A-frags) tile vs 2048 targets.
// 2x2 register blocking: each B-fragment LDS read feeds 2 MFMAs; B tiles are
// processed in pairs so the min-update fuses to v_min3_f32 (1 op / reg / pair
// per accumulator instead of 2) -> LDS cyc/MFMA 12->6, VALU min cyc/MFMA 8->4.
// Staging via global_load_lds width=16 (no VGPR round-trip, no ds_write).
// C/D: col = lane&31, row = (reg&3) + 8*(reg>>2) + 4*(lane>>5)  [m74/m101].
// ---------------------------------------------------------------------------
__global__ __launch_bounds__(THREADS, 4)
void chamfer_min_kernel(const float* __restrict__ pred,
                        const float* __restrict__ target,
                        const h8* __restrict__ trans_lo,
                        const h8* __restrict__ trans_hi,
                        float* __restrict__ partial)
{
    __shared__ uint4 slo[CHUNK];   // 16 KB
    __shared__ uint4 shi[CHUNK];   // 16 KB

    const int tid  = threadIdx.x;
    const int lane = tid & 63;
    const int wave = tid >> 6;
    const int n    = lane & 31;
    const int hi   = lane >> 5;

    const int bid = blockIdx.x;
    const int ts  = bid & 3;                  // target quarter
    const int qg  = (bid >> 2) & 31;          // query group (256 queries)
    const int b   = (bid >> 7) & 3;
    const int dir = bid >> 9;                 // 0: q=pred,db=target

    const int  qtbase = qg * 256 + wave * 64; // 64 queries per wave
    const int  tbase  = ts * THALF;
    const int  darr   = dir ^ 1;              // db array index in trans
    const float* qraw = ((dir == 0) ? pred : target) + (size_t)b * NPTS * 3;

    // ---- build the two A fragments (once) ----
    const h8 afrag0 = make_afrag(qraw + (size_t)(qtbase + n) * 3, hi);
    const h8 afrag1 = make_afrag(qraw + (size_t)(qtbase + 32 + n) * 3, hi);

    float mn0[16], mn1[16];
    #pragma unroll
    for (int i = 0; i < 16; ++i) { mn0[i] = 3.0e38f; mn1[i] = 3.0e38f; }

    const size_t gbase = (size_t)(darr * 4 + b) * NPTS + tbase;
    const h8* bsrc = hi ? (const h8*)shi : (const h8*)slo;
    const f16v zc = {};

    for (int c = 0; c < NCHUNKS; ++c) {
        // ---- async stage chunk: 8 x global_load_lds_dwordx4 per thread ----
        const size_t cb = gbase + (size_t)c * CHUNK;
        #pragma unroll
        for (int r = 0; r < 4; ++r) {
            glds16(((const uint4*)trans_lo) + cb + r * THREADS + tid,
                   &slo[r * THREADS + tid]);
            glds16(((const uint4*)trans_hi) + cb + r * THREADS + tid,
                   &shi[r * THREADS + tid]);
        }
        __syncthreads();   // compiler drains vmcnt(0) before s_barrier

        // ---- 16 pairs of B tiles: 2 ds_reads feed 4 MFMAs ----
        for (int tp = 0; tp < CHUNK / 64; ++tp) {
            const h8 b0 = bsrc[tp * 64 + n];
            const h8 b1 = bsrc[tp * 64 + 32 + n];

            const f16v d00 = __builtin_amdgcn_mfma_f32_32x32x16_f16(afrag0, b0, zc, 0, 0, 0);
            const f16v d01 = __builtin_amdgcn_mfma_f32_32x32x16_f16(afrag0, b1, zc, 0, 0, 0);
            #pragma unroll
            for (int i = 0; i < 16; ++i)
                mn0[i] = fminf(fminf(d00[i], d01[i]), mn0[i]);   // -> v_min3_f32

            const f16v d10 = __builtin_amdgcn_mfma_f32_32x32x16_f16(afrag1, b0, zc, 0, 0, 0);
            const f16v d11 = __builtin_amdgcn_mfma_f32_32x32x16_f16(afrag1, b1, zc, 0, 0, 0);
            #pragma unroll
            for (int i = 0; i < 16; ++i)
                mn1[i] = fminf(fminf(d10[i], d11[i]), mn1[i]);   // -> v_min3_f32
        }
        __syncthreads();
    }

    // ---- butterfly min over the 32 columns ----
    #pragma unroll
    for (int mask = 1; mask <= 16; mask <<= 1) {
        #pragma unroll
        for (int i = 0; i < 16; ++i) {
            mn0[i] = fminf(mn0[i], __shfl_xor(mn0[i], mask, 64));
            mn1[i] = fminf(mn1[i], __shfl_xor(mn1[i], mask, 64));
        }
    }

    // ---- one lane per half writes its 2x16 rows ----
    if (n == 0) {
        float* dst = partial + (size_t)ts * NQTOT
                   + (size_t)(dir * 4 + b) * NPTS + qtbase;
        #pragma unroll
        for (int i = 0; i < 16; ++i) {
            const int row = (i & 3) + 8 * (i >> 2) + 4 * hi;
            dst[row]      = mn0[i];
            dst[32 + row] = mn1[i];
        }
    }
}

// ---------------------------------------------------------------------------
// K2: merge target quarters, add |q|^2 (f32, exact), clamp, sqrt, block-sum.
// ---------------------------------------------------------------------------
__global__ __launch_bounds__(THREADS)
void chamfer_reduce1(const float* __restrict__ partial,
                     const float* __restrict__ pred,
                     const float* __restrict__ target,
                     float* __restrict__ bsum)
{
    const int tid = threadIdx.x;
    const int i   = blockIdx.x * THREADS + tid;     // 0..65535

    const float m01 = fminf(partial[i],                 partial[NQTOT + i]);
    const float m23 = fminf(partial[2 * NQTOT + i],     partial[3 * NQTOT + i]);
    const float m   = fminf(m01, m23);

    const int dir  = i >> 15;
    const int rest = i & 32767;                     // b*8192 + q
    const float* qp = ((dir == 0) ? pred : target) + (size_t)rest * 3;
    const float x = qp[0], y = qp[1], z = qp[2];
    const float qq = fmaf(x, x, fmaf(y, y, z * z));

    float acc = sqrtf(fmaxf(qq + m, 1e-12f));

    #pragma unroll
    for (int off = 32; off > 0; off >>= 1)
        acc += __shfl_down(acc, off, 64);

    __shared__ float wsum[4];
    if ((tid & 63) == 0) wsum[tid >> 6] = acc;
    __syncthreads();
    if (tid == 0) bsum[blockIdx.x] = wsum[0] + wsum[1] + wsum[2] + wsum[3];
}

// K3: sum 256 block sums, write mean over batches
__global__ __launch_bounds__(THREADS)
void chamfer_reduce2(const float* __restrict__ bsum,
                     float* __restrict__ out)
{
    const int tid = threadIdx.x;
    float v = bsum[tid];
    #pragma unroll
    for (int off = 32; off > 0; off >>= 1)
        v += __shfl_down(v, off, 64);

    __shared__ float wsum[4];
    if ((tid & 63) == 0) wsum[tid >> 6] = v;
    __syncthreads();
    if (tid == 0) out[0] = (wsum[0] + wsum[1] + wsum[2] + wsum[3]) * (1.0f / BATCH);
}

extern "C" void kernel_launch(void* const* d_in, const int* in_sizes, int n_in,
                              void* d_out, int out_size, void* d_ws, size_t ws_size,
                              hipStream_t stream)
{
    const float* pred   = (const float*)d_in[0];
    const float* target = (const float*)d_in[1];
    float* out          = (float*)d_out;

    // ws layout: trans_lo 1 MB | trans_hi 1 MB | partial 1 MB | bsum 1 KB
    h8*    trans_lo = (h8*)d_ws;                               // 65536 recs
    h8*    trans_hi = (h8*)((char*)d_ws + (size_t)65536 * 16);
    float* partial  = (float*)((char*)d_ws + (size_t)131072 * 16);
    float* bsum     = partial + (size_t)TSPLIT * NQTOT;

    chamfer_transform<<<NQTOT / THREADS, THREADS, 0, stream>>>(
        pred, target, trans_lo, trans_hi);   // 256 blocks

    chamfer_min_kernel<<<2 * BATCH * 32 * TSPLIT, THREADS, 0, stream>>>(
        pred, target, trans_lo, trans_hi, partial);   // 1024 blocks

    chamfer_reduce1<<<NQTOT / THREADS, THREADS, 0, stream>>>(
        partial, pred, target, bsum);   // 256 blocks

    chamfer_reduce2<<<1, THREADS, 0, stream>>>(bsum, out);
}

// Round 2
// 83.447 us; speedup vs baseline: 1.0252x; 1.0252x over previous
//
#include <hip/hip_runtime.h>
#include <math.h>

#define BATCH   4
#define NPTS    8192
#define THREADS 256
#define NQTOT   (2 * BATCH * NPTS)      // 65536 (dir,b,query) triples
#define TSPLIT  4                       // target quarters per (dir,b,qgroup)
#define THALF   (NPTS / TSPLIT)         // 2048 targets per block

typedef _Float16 h8  __attribute__((ext_vector_type(8)));    // 4 VGPRs
typedef float    f16v __attribute__((ext_vector_type(16)));  // 16 VGPRs

// ---------------------------------------------------------------------------
// K0: transform both point clouds into MFMA-ready split-f16 B-records,
// INTERLEAVED so one wave's 64-lane fragment read is a single contiguous 1 KB
// block (lane n, half hi reads record 2*(t*32+n)+hi).
// Point t -> th (f16) + tl (f16 residual), t~ = th+tl accurate to ~2.5e-7.
// lo record (K slots 0..7):  [-2thx,-2thy,-2thz, tth, -2thx,-2thy,-2thz, ttl]
// hi record (K slots 8..15): [-2tlx,-2tly,-2tlz, 0,0,0,0,0]
// Paired with A = [qhx,qhy,qhz,1, qlx,qly,qlz,1 | qhx,qhy,qhz,0,...] this
// makes one mfma_f32_32x32x16_f16 compute  tt - 2 q~.t~  exactly up to the
// omitted ql.tl term (~2e-5 absolute on sq).
// ---------------------------------------------------------------------------
__global__ __launch_bounds__(THREADS)
void chamfer_transform(const float* __restrict__ pred,
                       const float* __restrict__ target,
                       h8* __restrict__ trans_il)   // 65536 x 2 records
{
    const int p   = blockIdx.x * THREADS + threadIdx.x;   // 0..65535
    const int arr = p >> 15;                               // 0=pred, 1=target
    const int pb  = p & 32767;                             // (b*8192 + q)

    const float* src = (arr ? target : pred) + (size_t)pb * 3;
    const float x = src[0], y = src[1], z = src[2];

    const _Float16 hx = (_Float16)x;  const float lxf = x - (float)hx;
    const _Float16 hy = (_Float16)y;  const float lyf = y - (float)hy;
    const _Float16 hz = (_Float16)z;  const float lzf = z - (float)hz;
    const _Float16 lx = (_Float16)lxf, ly = (_Float16)lyf, lz = (_Float16)lzf;

    // |t~|^2 in f32 from the split coords (consistency with the cross term)
    const float tx = (float)hx + (float)lx;
    const float ty = (float)hy + (float)ly;
    const float tz = (float)hz + (float)lz;
    const float tt = fmaf(tx, tx, fmaf(ty, ty, tz * tz));
    const _Float16 tth = (_Float16)tt;
    const _Float16 ttl = (_Float16)(tt - (float)tth);

    const _Float16 n2 = (_Float16)(-2.0f);
    h8 lo = { n2 * hx, n2 * hy, n2 * hz, tth,
              n2 * hx, n2 * hy, n2 * hz, ttl };
    h8 hi = { n2 * lx, n2 * ly, n2 * lz, (_Float16)0.0f,
              (_Float16)0.0f, (_Float16)0.0f, (_Float16)0.0f, (_Float16)0.0f };

    trans_il[2 * p]     = lo;
    trans_il[2 * p + 1] = hi;
}

// ---------------------------------------------------------------------------
// A-fragment builder: m = lane&31, k = 8*(lane>>5)+j  (32x32x16 f16 layout).
// ---------------------------------------------------------------------------
__device__ __forceinline__ h8 make_afrag(const float* __restrict__ qp, const int hi)
{
    const float x = qp[0], y = qp[1], z = qp[2];
    const _Float16 hx = (_Float16)x; const _Float16 lx = (_Float16)(x - (float)hx);
    const _Float16 hy = (_Float16)y; const _Float16 ly = (_Float16)(y - (float)hy);
    const _Float16 hz = (_Float16)z; const _Float16 lz = (_Float16)(z - (float)hz);
    const _Float16 one  = (_Float16)1.0f;
    const _Float16 zero = (_Float16)0.0f;
    if (hi == 0) return (h8){hx, hy, hz, one, lx, ly, lz, one};
    return (h8){hx, hy, hz, zero, zero, zero, zero, zero};
}

// ---------------------------------------------------------------------------
// K1: per-wave 64-query (2 A-frags) tile vs 2048 targets.
// NO LDS: the whole B dataset is 2 MB and L2-resident (fits each XCD's 4 MB
// L2), so fragments are read straight from global — one contiguous 1 KB
// wave-transaction per tile.  This deletes the staging loads, both barriers
// (each drained vmcnt(0) for all waves), LDS address VALU, and the 32 KB
// LDS occupancy constraint; the loop is now free-running so loads pipeline
// arbitrarily deep.
// min3 pairing: each pair of B tiles folds with v_min3_f32 (8 VALU/MFMA).
// D-tiles consumed in two pairs so at most 2 (32 VGPR) are live at once.
// C/D: col = lane&31, row = (reg&3) + 8*(reg>>2) + 4*(lane>>5)  [m74/m101].
// ---------------------------------------------------------------------------
__global__ __launch_bounds__(THREADS, 4)
void chamfer_min_kernel(const float* __restrict__ pred,
                        const float* __restrict__ target,
                        const h8* __restrict__ trans_il,
                        float* __restrict__ partial)
{
    const int tid  = threadIdx.x;
    const int lane = tid & 63;
    const int wave = tid >> 6;
    const int n    = lane & 31;
    const int hi   = lane >> 5;

    const int bid = blockIdx.x;
    const int ts  = bid & 3;                  // target quarter
    const int qg  = (bid >> 2) & 31;          // query group (256 queries)
    const int b   = (bid >> 7) & 3;
    const int dir = bid >> 9;                 // 0: q=pred,db=target

    const int  qtbase = qg * 256 + wave * 64; // 64 queries per wave
    const int  tbase  = ts * THALF;
    const int  darr   = dir ^ 1;              // db array index in trans
    const float* qraw = ((dir == 0) ? pred : target) + (size_t)b * NPTS * 3;

    // ---- build the two A fragments (once) ----
    const h8 afrag0 = make_afrag(qraw + (size_t)(qtbase + n) * 3, hi);
    const h8 afrag1 = make_afrag(qraw + (size_t)(qtbase + 32 + n) * 3, hi);

    float mn0[16], mn1[16];
    #pragma unroll
    for (int i = 0; i < 16; ++i) { mn0[i] = 3.0e38f; mn1[i] = 3.0e38f; }

    // per-lane fragment pointer: record 2*(gbase + t + n) + hi
    const size_t gbase = (size_t)(darr * 4 + b) * NPTS + tbase;
    const h8* bp = trans_il + 2 * (gbase + n) + hi;
    const f16v zc = {};

    #pragma unroll 2
    for (int tp = 0; tp < THALF / 64; ++tp) {
        const h8 b0 = bp[tp * 128];           // tile 2*tp   (byte off tp*2048)
        const h8 b1 = bp[tp * 128 + 64];      // tile 2*tp+1 (+1024)

        const f16v d00 = __builtin_amdgcn_mfma_f32_32x32x16_f16(afrag0, b0, zc, 0, 0, 0);
        const f16v d01 = __builtin_amdgcn_mfma_f32_32x32x16_f16(afrag0, b1, zc, 0, 0, 0);
        #pragma unroll
        for (int i = 0; i < 16; ++i)
            mn0[i] = fminf(fminf(d00[i], d01[i]), mn0[i]);   // -> v_min3_f32

        const f16v d10 = __builtin_amdgcn_mfma_f32_32x32x16_f16(afrag1, b0, zc, 0, 0, 0);
        const f16v d11 = __builtin_amdgcn_mfma_f32_32x32x16_f16(afrag1, b1, zc, 0, 0, 0);
        #pragma unroll
        for (int i = 0; i < 16; ++i)
            mn1[i] = fminf(fminf(d10[i], d11[i]), mn1[i]);   // -> v_min3_f32
    }

    // ---- butterfly min over the 32 columns ----
    #pragma unroll
    for (int mask = 1; mask <= 16; mask <<= 1) {
        #pragma unroll
        for (int i = 0; i < 16; ++i) {
            mn0[i] = fminf(mn0[i], __shfl_xor(mn0[i], mask, 64));
            mn1[i] = fminf(mn1[i], __shfl_xor(mn1[i], mask, 64));
        }
    }

    // ---- one lane per half writes its 2x16 rows ----
    if (n == 0) {
        float* dst = partial + (size_t)ts * NQTOT
                   + (size_t)(dir * 4 + b) * NPTS + qtbase;
        #pragma unroll
        for (int i = 0; i < 16; ++i) {
            const int row = (i & 3) + 8 * (i >> 2) + 4 * hi;
            dst[row]      = mn0[i];
            dst[32 + row] = mn1[i];
        }
    }
}

// ---------------------------------------------------------------------------
// K2: merge target quarters, add |q|^2 (f32, exact), clamp, sqrt, block-sum.
// ---------------------------------------------------------------------------
__global__ __launch_bounds__(THREADS)
void chamfer_reduce1(const float* __restrict__ partial,
                     const float* __restrict__ pred,
                     const float* __restrict__ target,
                     float* __restrict__ bsum)
{
    const int tid = threadIdx.x;
    const int i   = blockIdx.x * THREADS + tid;     // 0..65535

    const float m01 = fminf(partial[i],                 partial[NQTOT + i]);
    const float m23 = fminf(partial[2 * NQTOT + i],     partial[3 * NQTOT + i]);
    const float m   = fminf(m01, m23);

    const int dir  = i >> 15;
    const int rest = i & 32767;                     // b*8192 + q
    const float* qp = ((dir == 0) ? pred : target) + (size_t)rest * 3;
    const float x = qp[0], y = qp[1], z = qp[2];
    const float qq = fmaf(x, x, fmaf(y, y, z * z));

    float acc = sqrtf(fmaxf(qq + m, 1e-12f));

    #pragma unroll
    for (int off = 32; off > 0; off >>= 1)
        acc += __shfl_down(acc, off, 64);

    __shared__ float wsum[4];
    if ((tid & 63) == 0) wsum[tid >> 6] = acc;
    __syncthreads();
    if (tid == 0) bsum[blockIdx.x] = wsum[0] + wsum[1] + wsum[2] + wsum[3];
}

// K3: sum 256 block sums, write mean over batches
__global__ __launch_bounds__(THREADS)
void chamfer_reduce2(const float* __restrict__ bsum,
                     float* __restrict__ out)
{
    const int tid = threadIdx.x;
    float v = bsum[tid];
    #pragma unroll
    for (int off = 32; off > 0; off >>= 1)
        v += __shfl_down(v, off, 64);

    __shared__ float wsum[4];
    if ((tid & 63) == 0) wsum[tid >> 6] = v;
    __syncthreads();
    if (tid == 0) out[0] = (wsum[0] + wsum[1] + wsum[2] + wsum[3]) * (1.0f / BATCH);
}

extern "C" void kernel_launch(void* const* d_in, const int* in_sizes, int n_in,
                              void* d_out, int out_size, void* d_ws, size_t ws_size,
                              hipStream_t stream)
{
    const float* pred   = (const float*)d_in[0];
    const float* target = (const float*)d_in[1];
    float* out          = (float*)d_out;

    // ws layout: trans_il 2 MB | partial 1 MB | bsum 1 KB
    h8*    trans_il = (h8*)d_ws;                               // 131072 recs
    float* partial  = (float*)((char*)d_ws + (size_t)131072 * 16);
    float* bsum     = partial + (size_t)TSPLIT * NQTOT;

    chamfer_transform<<<NQTOT / THREADS, THREADS, 0, stream>>>(
        pred, target, trans_il);   // 256 blocks

    chamfer_min_kernel<<<2 * BATCH * 32 * TSPLIT, THREADS, 0, stream>>>(
        pred, target, trans_il, partial);   // 1024 blocks

    chamfer_reduce1<<<NQTOT / THREADS, THREADS, 0, stream>>>(
        partial, pred, target, bsum);   // 256 blocks

    chamfer_reduce2<<<1, THREADS, 0, stream>>>(bsum, out);
}

// Round 3
// 82.004 us; speedup vs baseline: 1.0432x; 1.0176x over previous
//
#include <hip/hip_runtime.h>
#include <math.h>

#define BATCH   4
#define NPTS    8192
#define THREADS 256
#define NQTOT   (2 * BATCH * NPTS)      // 65536 (dir,b,query) triples
#define TPW     2048                    // targets per wave (4 waves cover 8192)

typedef _Float16 h8  __attribute__((ext_vector_type(8)));    // 4 VGPRs
typedef float    f16v __attribute__((ext_vector_type(16)));  // 16 VGPRs

// ---------------------------------------------------------------------------
// K0: transform both point clouds into MFMA-ready split-f16 B-records,
// INTERLEAVED so one wave's 64-lane fragment read is a single contiguous 1 KB
// block (lane n, half hi reads record 2*(t*32+n)+hi).
// Point t -> th (f16) + tl (f16 residual), t~ = th+tl accurate to ~2.5e-7.
// lo record (K slots 0..7):  [-2thx,-2thy,-2thz, tth, -2thx,-2thy,-2thz, ttl]
// hi record (K slots 8..15): [-2tlx,-2tly,-2tlz, 0,0,0,0,0]
// Paired with A = [qhx,qhy,qhz,1, qlx,qly,qlz,1 | qhx,qhy,qhz,0,...] one
// mfma_f32_32x32x16_f16 computes  tt - 2 q~.t~  (ql.tl term omitted,
// ~2e-5 absolute on sq).
// ---------------------------------------------------------------------------
__global__ __launch_bounds__(THREADS)
void chamfer_transform(const float* __restrict__ pred,
                       const float* __restrict__ target,
                       h8* __restrict__ trans_il)   // 65536 x 2 records
{
    const int p   = blockIdx.x * THREADS + threadIdx.x;   // 0..65535
    const int arr = p >> 15;                               // 0=pred, 1=target
    const int pb  = p & 32767;                             // (b*8192 + q)

    const float* src = (arr ? target : pred) + (size_t)pb * 3;
    const float x = src[0], y = src[1], z = src[2];

    const _Float16 hx = (_Float16)x;  const float lxf = x - (float)hx;
    const _Float16 hy = (_Float16)y;  const float lyf = y - (float)hy;
    const _Float16 hz = (_Float16)z;  const float lzf = z - (float)hz;
    const _Float16 lx = (_Float16)lxf, ly = (_Float16)lyf, lz = (_Float16)lzf;

    const float tx = (float)hx + (float)lx;
    const float ty = (float)hy + (float)ly;
    const float tz = (float)hz + (float)lz;
    const float tt = fmaf(tx, tx, fmaf(ty, ty, tz * tz));
    const _Float16 tth = (_Float16)tt;
    const _Float16 ttl = (_Float16)(tt - (float)tth);

    const _Float16 n2 = (_Float16)(-2.0f);
    h8 lo = { n2 * hx, n2 * hy, n2 * hz, tth,
              n2 * hx, n2 * hy, n2 * hz, ttl };
    h8 hi = { n2 * lx, n2 * ly, n2 * lz, (_Float16)0.0f,
              (_Float16)0.0f, (_Float16)0.0f, (_Float16)0.0f, (_Float16)0.0f };

    trans_il[2 * p]     = lo;
    trans_il[2 * p + 1] = hi;
}

// ---------------------------------------------------------------------------
// A-fragment builder: m = lane&31, k = 8*(lane>>5)+j  (32x32x16 f16 layout).
// ---------------------------------------------------------------------------
__device__ __forceinline__ h8 make_afrag(const float* __restrict__ qp, const int hi)
{
    const float x = qp[0], y = qp[1], z = qp[2];
    const _Float16 hx = (_Float16)x; const _Float16 lx = (_Float16)(x - (float)hx);
    const _Float16 hy = (_Float16)y; const _Float16 ly = (_Float16)(y - (float)hy);
    const _Float16 hz = (_Float16)z; const _Float16 lz = (_Float16)(z - (float)hz);
    const _Float16 one  = (_Float16)1.0f;
    const _Float16 zero = (_Float16)0.0f;
    if (hi == 0) return (h8){hx, hy, hz, one, lx, ly, lz, one};
    return (h8){hx, hy, hz, zero, zero, zero, zero, zero};
}

// ---------------------------------------------------------------------------
// K1 (fused): block = 64 queries; its 4 waves each cover a 2048-target
// quarter of ALL 8192 targets (B from L2, 2 MB dataset, no staging, no
// barriers in the hot loop).  After the per-wave column butterfly, a 1 KB
// LDS merge completes the min across waves IN-BLOCK, so the epilogue can
// fuse |q|^2 + sqrt + sum and emit ONE float per block.  This deletes the
// partial buffer (1 MB round-trip) and the separate merge kernel (one
// fewer dispatch).
// __launch_bounds__(256,2): 256-VGPR cap — the 2x2 blocking + unroll-4
// load pipeline stays spill-free (the (256,4)=128-VGPR cap in R1/R2 was
// the suspected spill source).
// C/D: col = lane&31, row = (reg&3) + 8*(reg>>2) + 4*(lane>>5)  [m74/m101].
// ---------------------------------------------------------------------------
__global__ __launch_bounds__(THREADS, 2)
void chamfer_min_kernel(const float* __restrict__ pred,
                        const float* __restrict__ target,
                        const h8* __restrict__ trans_il,
                        float* __restrict__ bsum)
{
    __shared__ float lmn[2][4][2][16];   // [set][wave][hi][reg] = 1 KB

    const int tid  = threadIdx.x;
    const int lane = tid & 63;
    const int wave = tid >> 6;
    const int n    = lane & 31;
    const int hi   = lane >> 5;

    const int bid = blockIdx.x;           // dir*512 + b*128 + qt
    const int qt  = bid & 127;
    const int b   = (bid >> 7) & 3;
    const int dir = bid >> 9;             // 0: q=pred, targets=target

    const int  qtbase = qt * 64;
    const int  darr   = dir ^ 1;          // target-array index in trans
    const float* qraw = ((dir == 0) ? pred : target) + (size_t)b * NPTS * 3;

    // ---- two A fragments: queries qtbase+n and qtbase+32+n ----
    const h8 afrag0 = make_afrag(qraw + (size_t)(qtbase + n) * 3, hi);
    const h8 afrag1 = make_afrag(qraw + (size_t)(qtbase + 32 + n) * 3, hi);

    float mn0[16], mn1[16];
    #pragma unroll
    for (int i = 0; i < 16; ++i) { mn0[i] = 3.0e38f; mn1[i] = 3.0e38f; }

    // wave w covers targets [w*TPW, (w+1)*TPW)
    const size_t gbase = (size_t)(darr * 4 + b) * NPTS + (size_t)wave * TPW;
    const h8* bp = trans_il + 2 * (gbase + n) + hi;
    const f16v zc = {};

    #pragma unroll 4
    for (int tp = 0; tp < TPW / 64; ++tp) {
        const h8 b0 = bp[tp * 128];           // tile 2*tp
        const h8 b1 = bp[tp * 128 + 64];      // tile 2*tp+1

        const f16v d00 = __builtin_amdgcn_mfma_f32_32x32x16_f16(afrag0, b0, zc, 0, 0, 0);
        const f16v d01 = __builtin_amdgcn_mfma_f32_32x32x16_f16(afrag0, b1, zc, 0, 0, 0);
        #pragma unroll
        for (int i = 0; i < 16; ++i)
            mn0[i] = fminf(fminf(d00[i], d01[i]), mn0[i]);   // -> v_min3_f32

        const f16v d10 = __builtin_amdgcn_mfma_f32_32x32x16_f16(afrag1, b0, zc, 0, 0, 0);
        const f16v d11 = __builtin_amdgcn_mfma_f32_32x32x16_f16(afrag1, b1, zc, 0, 0, 0);
        #pragma unroll
        for (int i = 0; i < 16; ++i)
            mn1[i] = fminf(fminf(d10[i], d11[i]), mn1[i]);   // -> v_min3_f32
    }

    // ---- butterfly min over the 32 columns (targets) within the wave ----
    #pragma unroll
    for (int mask = 1; mask <= 16; mask <<= 1) {
        #pragma unroll
        for (int i = 0; i < 16; ++i) {
            mn0[i] = fminf(mn0[i], __shfl_xor(mn0[i], mask, 64));
            mn1[i] = fminf(mn1[i], __shfl_xor(mn1[i], mask, 64));
        }
    }

    // ---- cross-wave merge via LDS ----
    if (n == 0) {
        #pragma unroll
        for (int i = 0; i < 16; ++i) {
            lmn[0][wave][hi][i] = mn0[i];
            lmn[1][wave][hi][i] = mn1[i];
        }
    }
    __syncthreads();

    // ---- wave 0: final min, |q|^2, sqrt, sum -> one float per block ----
    if (wave == 0) {
        const int set = lane & 1;          // 0: mn0 queries, 1: +32
        const int h2  = (lane >> 1) & 1;   // hi half
        const int i   = lane >> 2;         // reg index 0..15
        const float m = fminf(fminf(lmn[set][0][h2][i], lmn[set][1][h2][i]),
                              fminf(lmn[set][2][h2][i], lmn[set][3][h2][i]));
        const int r = (i & 3) + 8 * (i >> 2) + 4 * h2;       // row 0..31
        const int q = qtbase + 32 * set + r;
        const float* qp = qraw + (size_t)q * 3;              // L1-hot
        const float x = qp[0], y = qp[1], z = qp[2];
        const float qq = fmaf(x, x, fmaf(y, y, z * z));
        float acc = sqrtf(fmaxf(qq + m, 1e-12f));

        #pragma unroll
        for (int off = 32; off > 0; off >>= 1)
            acc += __shfl_down(acc, off, 64);
        if (lane == 0) bsum[bid] = acc;
    }
}

// ---------------------------------------------------------------------------
// K3: sum 1024 block sums, write mean over batches.
// ---------------------------------------------------------------------------
__global__ __launch_bounds__(THREADS)
void chamfer_reduce2(const float* __restrict__ bsum,
                     float* __restrict__ out)
{
    const int tid = threadIdx.x;
    float v = bsum[tid] + bsum[256 + tid] + bsum[512 + tid] + bsum[768 + tid];
    #pragma unroll
    for (int off = 32; off > 0; off >>= 1)
        v += __shfl_down(v, off, 64);

    __shared__ float wsum[4];
    if ((tid & 63) == 0) wsum[tid >> 6] = v;
    __syncthreads();
    if (tid == 0) out[0] = (wsum[0] + wsum[1] + wsum[2] + wsum[3]) * (1.0f / BATCH);
}

extern "C" void kernel_launch(void* const* d_in, const int* in_sizes, int n_in,
                              void* d_out, int out_size, void* d_ws, size_t ws_size,
                              hipStream_t stream)
{
    const float* pred   = (const float*)d_in[0];
    const float* target = (const float*)d_in[1];
    float* out          = (float*)d_out;

    // ws layout: trans_il 2 MB | bsum 4 KB
    h8*    trans_il = (h8*)d_ws;                               // 131072 recs
    float* bsum     = (float*)((char*)d_ws + (size_t)131072 * 16);

    chamfer_transform<<<NQTOT / THREADS, THREADS, 0, stream>>>(
        pred, target, trans_il);   // 256 blocks

    chamfer_min_kernel<<<2 * BATCH * 128, THREADS, 0, stream>>>(
        pred, target, trans_il, bsum);   // 1024 blocks

    chamfer_reduce2<<<1, THREADS, 0, stream>>>(bsum, out);
}